// Round 11
// baseline (223.437 us; speedup 1.0000x reference)
//
#include <hip/hip_runtime.h>
#include <math.h>

#define BB 8
#define PP 1000
#define NN 1000
#define EE 128
#define HH 8
#define DD 16

#define INV_SQRT_E 0.08838834764831845f   // 1/sqrt(128)
#define LOG2E      1.4426950408889634f
#define QSCALE     0.3606737602222409f     // (1/sqrt(16)) * log2(e), folded into Q at proj

typedef short short8_t __attribute__((ext_vector_type(8)));
typedef float f32x4    __attribute__((ext_vector_type(4)));
typedef float f32x16   __attribute__((ext_vector_type(16)));
typedef __bf16 bf16x4  __attribute__((ext_vector_type(4)));
typedef __bf16 bf16x8  __attribute__((ext_vector_type(8)));

__device__ __forceinline__ float sigmoid_fast(float x) {
    return 1.f / (1.f + __expf(-x));
}
__device__ __forceinline__ float tanh_fast(float x) {
    x = fminf(fmaxf(x, -15.f), 15.f);
    float e = __expf(2.f * x);
    return (e - 1.f) / (e + 1.f);
}

__device__ __forceinline__ f32x4 mfma16(short8_t a, short8_t b, f32x4 c) {
    return __builtin_amdgcn_mfma_f32_16x16x32_bf16(a, b, c, 0, 0, 0);
}
__device__ __forceinline__ f32x16 mfma32(short8_t a, short8_t b, f32x16 c) {
    return __builtin_amdgcn_mfma_f32_32x32x16_bf16(a, b, c, 0, 0, 0);
}

// sum across the 16 lanes of a DPP row (pure VALU butterfly)
__device__ __forceinline__ float sum16(float x) {
    int v;
    v = __builtin_amdgcn_update_dpp(0, __builtin_bit_cast(int, x), 0xB1, 0xF, 0xF, true);
    x += __builtin_bit_cast(float, v);
    v = __builtin_amdgcn_update_dpp(0, __builtin_bit_cast(int, x), 0x4E, 0xF, 0xF, true);
    x += __builtin_bit_cast(float, v);
    v = __builtin_amdgcn_update_dpp(0, __builtin_bit_cast(int, x), 0x141, 0xF, 0xF, true);
    x += __builtin_bit_cast(float, v);
    v = __builtin_amdgcn_update_dpp(0, __builtin_bit_cast(int, x), 0x140, 0xF, 0xF, true);
    x += __builtin_bit_cast(float, v);
    return x;
}

// ---------------------------------------------------------------------------
// K0: FUSED prep, fat grid-stride threads (16 floats each).
// Grid segments:
//  [0,1954)      emaskb = (bf16)(mask*log2e)  -- LOG2 DOMAIN  (8M elems)
//  [1954,2204)   nodesb = (bf16)nodes               (1.024M elems)
//  [2204,2829)   inb = concat(eln,attr,0) bf16      (8000x160)
//  [2829,2874)   Wtb = transposed bf16 weights      (9 x 5 k-tiles)
// Wtb offsets: 0:k_s 16384:v_s 32768:k_t 49152:v_t 65536:q_s 86016:q_t
//              106496:g 126976:c_s 143360:c_t
// ---------------------------------------------------------------------------
__global__ __launch_bounds__(256) void prep_kernel(
    const float* __restrict__ mask, const float* __restrict__ nodes,
    const float* __restrict__ eln,  const float* __restrict__ attr,
    const float* __restrict__ Wk_s, const float* __restrict__ Wv_s,
    const float* __restrict__ Wk_t, const float* __restrict__ Wv_t,
    const float* __restrict__ Wq_s, const float* __restrict__ Wq_t,
    const float* __restrict__ Wg,   const float* __restrict__ Wc_s,
    const float* __restrict__ Wc_t,
    __bf16* __restrict__ emaskb, __bf16* __restrict__ nodesb,
    __bf16* __restrict__ inb, __bf16* __restrict__ Wtb)
{
    const int bx = blockIdx.x;
    __shared__ float tile[32][129];
    if (bx < 1954) {
        int base = (bx * 256 + threadIdx.x) * 16;
        if (base < 8000000) {
            #pragma unroll
            for (int q = 0; q < 4; ++q) {
                float4 v = *(const float4*)&mask[base + q * 4];
                bf16x4 p = { (__bf16)(v.x * LOG2E), (__bf16)(v.y * LOG2E),
                             (__bf16)(v.z * LOG2E), (__bf16)(v.w * LOG2E) };
                *(bf16x4*)&emaskb[base + q * 4] = p;
            }
        }
    } else if (bx < 2204) {
        int base = ((bx - 1954) * 256 + threadIdx.x) * 16;   // 1,024,000 exact
        #pragma unroll
        for (int q = 0; q < 4; ++q) {
            float4 v = *(const float4*)&nodes[base + q * 4];
            bf16x4 p = { (__bf16)v.x, (__bf16)v.y, (__bf16)v.z, (__bf16)v.w };
            *(bf16x4*)&nodesb[base + q * 4] = p;
        }
    } else if (bx < 2829) {
        int t = (bx - 2204) * 256 + threadIdx.x;             // 160,000 exact
        int row = t / 20, seg = t - row * 20;
        bf16x8 o = {};
        if (seg < 16) {
            const float* p = &eln[(size_t)row * 128 + seg * 8];
            float4 a = *(const float4*)p, b = *(const float4*)(p + 4);
            o = bf16x8{ (__bf16)a.x, (__bf16)a.y, (__bf16)a.z, (__bf16)a.w,
                        (__bf16)b.x, (__bf16)b.y, (__bf16)b.z, (__bf16)b.w };
        } else if (seg == 16) {
            float4 a = *(const float4*)&attr[(size_t)row * 4];
            o = bf16x8{ (__bf16)a.x, (__bf16)a.y, (__bf16)a.z, (__bf16)a.w,
                        (__bf16)0.f, (__bf16)0.f, (__bf16)0.f, (__bf16)0.f };
        }
        *(bf16x8*)&inb[(size_t)row * 160 + seg * 8] = o;
    } else {
        int idx = bx - 2829;
        int m = idx / 5, kt = idx - m * 5;
        const float* srcs[9] = {Wk_s, Wv_s, Wk_t, Wv_t, Wq_s, Wq_t, Wg, Wc_s, Wc_t};
        const int   srcKs[9] = {128, 128, 128, 128, 132, 132, 132, 128, 128};
        const int   kpads[9] = {128, 128, 128, 128, 160, 160, 160, 128, 128};
        const size_t offs[9] = {0, 16384, 32768, 49152, 65536, 86016, 106496, 126976, 143360};
        const int kp = kpads[m];
        if (kt * 32 >= kp) return;
        const float* src = srcs[m];
        const int sK = srcKs[m];
        const size_t off = offs[m];
        const int tid = threadIdx.x;
        for (int j = tid; j < 32 * 128; j += 256) {
            int kk = j >> 7, n = j & 127;
            int k = kt * 32 + kk;
            tile[kk][n] = (k < sK) ? src[(size_t)k * 128 + n] : 0.f;
        }
        __syncthreads();
        for (int j = tid; j < 32 * 128; j += 256) {
            int n = j >> 5, kk = j & 31;
            Wtb[off + (size_t)n * kp + kt * 32 + kk] = (__bf16)tile[kk][n];
        }
    }
}

// ---------------------------------------------------------------------------
// K1: MFMA projections. Wave = 16 rows x 128 cols. blockIdx.y = wsel:
// 0..3 kv (A=nodesb,K=128), 4..5 q (A=inb,K=160, scaled by log2e/sqrt(D)).
// ---------------------------------------------------------------------------
template<int NC>
__device__ __forceinline__ void proj_body(
    const __bf16* __restrict__ A, const __bf16* __restrict__ W,
    f32x4 acc[8], int r0, int quad, int lq)
{
    const int K = NC * 32;
    short8_t aF[NC];
    #pragma unroll
    for (int c = 0; c < NC; ++c)
        aF[c] = *(const short8_t*)&A[(size_t)(r0 + lq) * K + c * 32 + quad * 8];
    #pragma unroll
    for (int nt = 0; nt < 8; ++nt) {
        acc[nt] = f32x4{0.f, 0.f, 0.f, 0.f};
        #pragma unroll
        for (int c = 0; c < NC; ++c) {
            short8_t bF = *(const short8_t*)&W[(size_t)(nt * 16 + lq) * K + c * 32 + quad * 8];
            acc[nt] = mfma16(aF[c], bF, acc[nt]);
        }
    }
}

__global__ __launch_bounds__(256) void proj_mfma_kernel(
    const __bf16* __restrict__ nodesb, const __bf16* __restrict__ inb,
    const __bf16* __restrict__ Wtb,
    __bf16* __restrict__ kb_s, __bf16* __restrict__ vt_s,
    __bf16* __restrict__ kb_t, __bf16* __restrict__ vt_t,
    __bf16* __restrict__ qb_s, __bf16* __restrict__ qb_t)
{
    const int wsel = blockIdx.y;
    const int wave = threadIdx.x >> 6, lane = threadIdx.x & 63;
    const int quad = lane >> 4, lq = lane & 15;
    const int r0 = blockIdx.x * 64 + wave * 16;

    f32x4 acc[8];
    if (wsel < 4) {
        proj_body<4>(nodesb, Wtb + (size_t)wsel * 16384, acc, r0, quad, lq);
    } else {
        proj_body<5>(inb, Wtb + 65536 + (size_t)(wsel - 4) * 20480, acc, r0, quad, lq);
    }

    if (wsel == 0 || wsel == 2) {
        __bf16* O = (wsel == 0) ? kb_s : kb_t;
        #pragma unroll
        for (int r = 0; r < 4; ++r) {
            int m = r0 + quad * 4 + r;
            int b = m / 1000, n = m - b * 1000;
            #pragma unroll
            for (int nt = 0; nt < 8; ++nt)
                O[(((size_t)(b * 8 + nt) * 1000 + n) << 4) + lq] = (__bf16)acc[nt][r];
        }
    } else if (wsel == 4 || wsel == 5) {
        __bf16* O = (wsel == 4) ? qb_s : qb_t;
        #pragma unroll
        for (int r = 0; r < 4; ++r) {
            int m = r0 + quad * 4 + r;
            int b = m / 1000, n = m - b * 1000;
            #pragma unroll
            for (int nt = 0; nt < 8; ++nt)
                O[(((size_t)(b * 8 + nt) * 1000 + n) << 4) + lq] =
                    (__bf16)(acc[nt][r] * QSCALE);
        }
    } else {
        __bf16* O = (wsel == 1) ? vt_s : vt_t;
        #pragma unroll
        for (int r = 0; r < 4; ++r) {
            int m = r0 + quad * 4 + r;
            int b = m / 1000, n = m - b * 1000;
            int rr = n & 31;
            int pos = (n & ~31) + ((rr < 16) ? (rr << 1) : (((rr - 16) << 1) | 1));
            #pragma unroll
            for (int nt = 0; nt < 8; ++nt)
                O[(((size_t)(b * 8 + nt) * 16 + lq) << 10) + pos] = (__bf16)acc[nt][r];
        }
    }
}

// ---------------------------------------------------------------------------
// K2: MFMA flash attention v13: branch-fused + LDS block-XOR swizzle (r10)
// + mask folded into the mfma32 C OPERAND: the prefetched bf16 mask tile is
// converted to f32 at prefetch time (off the critical path) and passed as C,
// so s = K.Q + m in one instruction — the 32 per-tile v_adds are gone.
// (R8's C-operand failure was mask-from-memory latency; prefetch removes it.)
// ---------------------------------------------------------------------------
__global__ __launch_bounds__(256) void attn_mfma_kernel(
    const __bf16* __restrict__ qb_s, const __bf16* __restrict__ qb_t,
    const __bf16* __restrict__ kb_s, const __bf16* __restrict__ kb_t,
    const __bf16* __restrict__ vt_s, const __bf16* __restrict__ vt_t,
    const __bf16* __restrict__ emaskb,
    __bf16* __restrict__ att_s, __bf16* __restrict__ att_t)
{
    const int b    = blockIdx.z;
    const int wave = threadIdx.x >> 6;
    const int h    = blockIdx.y * 4 + wave;
    const int lane = threadIdx.x & 63;
    const int quad = lane >> 4, lq = lane & 15;
    const int col  = lane & 31;         // 32x32 column (= p for scores)
    const int half = lane >> 5;         // 32x32 row-half
    const int bh = b * HH + h;
    const int p0 = blockIdx.x * 32;

    // S[wave][parity][branch][p][slot], slot-blocks XOR-swizzled by row
    __shared__ __align__(16) __bf16 S[4][2][2][32][40];

    // write-side swizzle for this lane's P row (row = col)
    const int cw = (col >> 3) & 3;
    // read-side swizzled byte offsets (row = t*16+lq, block = quad ^ cr_t)
    const int r0q = 8 * (quad ^ ((lq >> 3) & 1));        // t=0: cr = 0|1
    const int r1q = 8 * (quad ^ (2 | ((lq >> 3) & 1)));  // t=1: cr = 2|3

    int pq = p0 + col; if (pq > 999) pq = 999;
    short8_t qS = *(const short8_t*)&qb_s[(((size_t)bh * 1000 + pq) << 4) + half * 8];
    short8_t qT = *(const short8_t*)&qb_t[(((size_t)bh * 1000 + pq) << 4) + half * 8];
    const __bf16* mp = emaskb + ((size_t)b * 1000 + pq) * 1000 + 4 * half;

    short8_t onesB = { (short)0x3F80, (short)0x3F80, (short)0x3F80, (short)0x3F80,
                       (short)0x3F80, (short)0x3F80, (short)0x3F80, (short)0x3F80 };

    f32x4 oS[2] = { {0.f,0.f,0.f,0.f}, {0.f,0.f,0.f,0.f} };
    f32x4 lS[2] = { {0.f,0.f,0.f,0.f}, {0.f,0.f,0.f,0.f} };
    f32x4 oT[2] = { {0.f,0.f,0.f,0.f}, {0.f,0.f,0.f,0.f} };
    f32x4 lT[2] = { {0.f,0.f,0.f,0.f}, {0.f,0.f,0.f,0.f} };

    const size_t kqoff = (((size_t)bh * 1000) << 4) + half * 8;
    const size_t voff  = (((size_t)bh * 16 + lq) << 10) + quad * 8;

    short8_t kScur = *(const short8_t*)&kb_s[kqoff + ((size_t)col << 4)];
    short8_t kTcur = *(const short8_t*)&kb_t[kqoff + ((size_t)col << 4)];
    short8_t vScur = *(const short8_t*)&vt_s[voff];
    short8_t vTcur = *(const short8_t*)&vt_t[voff];

    // current-tile mask as f32 C operand (prefetched + converted ahead of use)
    f32x16 mC;
    {
        bf16x4 m0[4];
        #pragma unroll
        for (int g = 0; g < 4; ++g) m0[g] = *(const bf16x4*)&mp[8 * g];
        #pragma unroll
        for (int g = 0; g < 4; ++g)
            #pragma unroll
            for (int j = 0; j < 4; ++j)
                mC[4 * g + j] = (float)m0[g][j];
    }

    #pragma unroll 2
    for (int n0 = 0; n0 < 992; n0 += 32) {
        const int par = (n0 >> 5) & 1;
        int nk = n0 + 32 + col; if (nk > 999) nk = 999;
        short8_t kSn = *(const short8_t*)&kb_s[kqoff + ((size_t)nk << 4)];
        short8_t kTn = *(const short8_t*)&kb_t[kqoff + ((size_t)nk << 4)];
        short8_t vSn = *(const short8_t*)&vt_s[voff + n0 + 32];
        short8_t vTn = *(const short8_t*)&vt_t[voff + n0 + 32];
        bf16x4 mn[4];
        #pragma unroll
        for (int g = 0; g < 4; ++g)
            mn[g] = *(const bf16x4*)&mp[n0 + 32 + 8 * g];

        // branch S scores: s = K.Q + mask (C operand)
        f32x16 sS = mfma32(kScur, qS, mC);
        #pragma unroll
        for (int g = 0; g < 4; ++g) {
            bf16x4 pk;
            #pragma unroll
            for (int j = 0; j < 4; ++j)
                pk[j] = (__bf16)__builtin_amdgcn_exp2f(sS[4 * g + j]);
            *(bf16x4*)&S[wave][par][0][col][8 * (g ^ cw) + 4 * half] = pk;
        }

        // branch T scores (latency hidden by PV-S below)
        f32x16 sT = mfma32(kTcur, qT, mC);

        {
            short8_t aP0 = *(const short8_t*)&S[wave][par][0][lq][r0q];
            oS[0] = mfma16(aP0, vScur, oS[0]);
            lS[0] = mfma16(aP0, onesB, lS[0]);
            short8_t aP1 = *(const short8_t*)&S[wave][par][0][16 + lq][r1q];
            oS[1] = mfma16(aP1, vScur, oS[1]);
            lS[1] = mfma16(aP1, onesB, lS[1]);
        }

        #pragma unroll
        for (int g = 0; g < 4; ++g) {
            bf16x4 pk;
            #pragma unroll
            for (int j = 0; j < 4; ++j)
                pk[j] = (__bf16)__builtin_amdgcn_exp2f(sT[4 * g + j]);
            *(bf16x4*)&S[wave][par][1][col][8 * (g ^ cw) + 4 * half] = pk;
        }

        {
            short8_t aP0 = *(const short8_t*)&S[wave][par][1][lq][r0q];
            oT[0] = mfma16(aP0, vTcur, oT[0]);
            lT[0] = mfma16(aP0, onesB, lT[0]);
            short8_t aP1 = *(const short8_t*)&S[wave][par][1][16 + lq][r1q];
            oT[1] = mfma16(aP1, vTcur, oT[1]);
            lT[1] = mfma16(aP1, onesB, lT[1]);
        }

        kScur = kSn; kTcur = kTn; vScur = vSn; vTcur = vTn;
        // convert next tile's mask (off the critical path of this tile)
        #pragma unroll
        for (int g = 0; g < 4; ++g)
            #pragma unroll
            for (int j = 0; j < 4; ++j)
                mC[4 * g + j] = (float)mn[g][j];
    }

    // tail: keys 992..999 == group g=0 of both halves; groups 1..3 zeroed
    // (XOR is a bijection on blocks 0..3, so writing all 4 g-blocks covers all)
    {
        f32x16 mCt = {};
        #pragma unroll
        for (int j = 0; j < 4; ++j) mCt[j] = mC[j];
        bf16x4 z = {};

        f32x16 sS = mfma32(kScur, qS, mCt);
        bf16x4 pkS;
        #pragma unroll
        for (int j = 0; j < 4; ++j)
            pkS[j] = (__bf16)__builtin_amdgcn_exp2f(sS[j]);
        *(bf16x4*)&S[wave][1][0][col][8 * (0 ^ cw) + 4 * half] = pkS;
        #pragma unroll
        for (int g = 1; g < 4; ++g)
            *(bf16x4*)&S[wave][1][0][col][8 * (g ^ cw) + 4 * half] = z;

        f32x16 sT = mfma32(kTcur, qT, mCt);

        {
            short8_t aP0 = *(const short8_t*)&S[wave][1][0][lq][r0q];
            oS[0] = mfma16(aP0, vScur, oS[0]);
            lS[0] = mfma16(aP0, onesB, lS[0]);
            short8_t aP1 = *(const short8_t*)&S[wave][1][0][16 + lq][r1q];
            oS[1] = mfma16(aP1, vScur, oS[1]);
            lS[1] = mfma16(aP1, onesB, lS[1]);
        }

        bf16x4 pkT;
        #pragma unroll
        for (int j = 0; j < 4; ++j)
            pkT[j] = (__bf16)__builtin_amdgcn_exp2f(sT[j]);
        *(bf16x4*)&S[wave][1][1][col][8 * (0 ^ cw) + 4 * half] = pkT;
        #pragma unroll
        for (int g = 1; g < 4; ++g)
            *(bf16x4*)&S[wave][1][1][col][8 * (g ^ cw) + 4 * half] = z;

        {
            short8_t aP0 = *(const short8_t*)&S[wave][1][1][lq][r0q];
            oT[0] = mfma16(aP0, vTcur, oT[0]);
            lT[0] = mfma16(aP0, onesB, lT[0]);
            short8_t aP1 = *(const short8_t*)&S[wave][1][1][16 + lq][r1q];
            oT[1] = mfma16(aP1, vTcur, oT[1]);
            lT[1] = mfma16(aP1, onesB, lT[1]);
        }
    }

    #pragma unroll
    for (int t = 0; t < 2; ++t)
        #pragma unroll
        for (int r = 0; r < 4; ++r) {
            int p = p0 + t * 16 + quad * 4 + r;
            if (p < 1000) {
                size_t oidx = ((size_t)b * 1000 + p) * 128 + h * 16 + lq;
                att_s[oidx] = (__bf16)(oS[t][r] / lS[t][r]);
                att_t[oidx] = (__bf16)(oT[t][r] / lT[t][r]);
            }
        }
}

// ---------------------------------------------------------------------------
// K3: MFMA combine WITH INLINE GATE, nt-PARALLEL: grid (125, 8) x 256.
// ---------------------------------------------------------------------------
__global__ __launch_bounds__(256) void combine_mfma_kernel(
    const __bf16* __restrict__ att_s, const __bf16* __restrict__ att_t,
    const __bf16* __restrict__ inb, const __bf16* __restrict__ Wtb,
    const float* __restrict__ bc_s, const float* __restrict__ bc_t,
    const float* __restrict__ bg, __bf16* __restrict__ gatedb)
{
    const int wave = threadIdx.x >> 6, lane = threadIdx.x & 63;
    const int quad = lane >> 4, lq = lane & 15;
    const int r0 = blockIdx.x * 64 + wave * 16;
    const int nt = blockIdx.y;                 // 0..7
    const __bf16* Wgp = Wtb + 106496;
    const __bf16* Ws  = Wtb + 126976;
    const __bf16* Wt  = Wtb + 143360;

    short8_t aS[4], aT[4], aG[5];
    #pragma unroll
    for (int c = 0; c < 4; ++c) {
        aS[c] = *(const short8_t*)&att_s[(size_t)(r0 + lq) * 128 + c * 32 + quad * 8];
        aT[c] = *(const short8_t*)&att_t[(size_t)(r0 + lq) * 128 + c * 32 + quad * 8];
    }
    #pragma unroll
    for (int c = 0; c < 5; ++c)
        aG[c] = *(const short8_t*)&inb[(size_t)(r0 + lq) * 160 + c * 32 + quad * 8];

    f32x4 accS = {0.f,0.f,0.f,0.f}, accT = accS, accG = accS;
    #pragma unroll
    for (int c = 0; c < 4; ++c) {
        short8_t bS = *(const short8_t*)&Ws[(size_t)(nt * 16 + lq) * 128 + c * 32 + quad * 8];
        short8_t bT = *(const short8_t*)&Wt[(size_t)(nt * 16 + lq) * 128 + c * 32 + quad * 8];
        accS = mfma16(aS[c], bS, accS);
        accT = mfma16(aT[c], bT, accT);
    }
    #pragma unroll
    for (int c = 0; c < 5; ++c) {
        short8_t bG = *(const short8_t*)&Wgp[(size_t)(nt * 16 + lq) * 160 + c * 32 + quad * 8];
        accG = mfma16(aG[c], bG, accG);
    }
    int f = nt * 16 + lq;
    float b1 = bc_s[f], b2 = bc_t[f], b3 = bg[f];
    #pragma unroll
    for (int r = 0; r < 4; ++r) {
        int m = r0 + quad * 4 + r;
        float g = sigmoid_fast(accG[r] + b3);
        float val = g * (accS[r] + b1) + (1.f - g) * (accT[r] + b2);
        gatedb[(size_t)m * 128 + f] = (__bf16)val;
    }
}

// ---------------------------------------------------------------------------
// K4: FUSED pointer scores + clip + log2-mask + row softmax -> probs in d_out.
// 8 waves (512 threads).
// ---------------------------------------------------------------------------
__global__ __launch_bounds__(512) void pointer_softmax_kernel(
    const __bf16* __restrict__ gb, const __bf16* __restrict__ nb,
    const __bf16* __restrict__ emaskb, float* __restrict__ out)
{
    const int b    = blockIdx.y;
    const int p0   = blockIdx.x * 16;
    const int wave = threadIdx.x >> 6;          // 0..7
    const int lane = threadIdx.x & 63;
    const int quad = lane >> 4, lq = lane & 15;

    __shared__ float Spart[8][16];

    short8_t aF[4];
    {
        int pp = p0 + lq; if (pp > 999) pp = 999;
        const __bf16* arow = gb + (((size_t)b * 1000 + pp) << 7) + quad * 8;
        #pragma unroll
        for (int kc = 0; kc < 4; ++kc) aF[kc] = *(const short8_t*)&arow[kc * 32];
    }

    float ev[8][4];
    float psum[4] = {0.f, 0.f, 0.f, 0.f};

    #pragma unroll
    for (int i = 0; i < 8; ++i) {
        const int nt = i * 8 + wave;          // 0..63
        const int nn = nt * 16 + lq;
        const bool nv = nn < 1000;
        int nc = nv ? nn : 999;
        const __bf16* brow = nb + (((size_t)b * 1000 + nc) << 7) + quad * 8;
        f32x4 acc = {0.f, 0.f, 0.f, 0.f};
        #pragma unroll
        for (int kc = 0; kc < 4; ++kc) {
            short8_t bF = *(const short8_t*)&brow[kc * 32];
            acc = mfma16(aF[kc], bF, acc);
        }
        #pragma unroll
        for (int r = 0; r < 4; ++r) {
            int p = p0 + quad * 4 + r;
            bool v = nv && (p < 1000);
            size_t midx = v ? ((size_t)b * 1000 + p) * 1000 + nn : 0;
            float m2 = (float)emaskb[midx];
            float sc = 10.f * tanh_fast(acc[r] * INV_SQRT_E);
            float ee = v ? __builtin_amdgcn_exp2f(sc * LOG2E + m2) : 0.f;
            ev[i][r] = ee;
            psum[r] += ee;
        }
    }

    #pragma unroll
    for (int r = 0; r < 4; ++r) psum[r] = sum16(psum[r]);
    if (lq == 0) {
        #pragma unroll
        for (int r = 0; r < 4; ++r) Spart[wave][quad * 4 + r] = psum[r];
    }
    __syncthreads();
    float inv[4];
    #pragma unroll
    for (int r = 0; r < 4; ++r) {
        int row = quad * 4 + r;
        float s = 0.f;
        #pragma unroll
        for (int wv = 0; wv < 8; ++wv) s += Spart[wv][row];
        inv[r] = 1.f / s;
    }

    #pragma unroll
    for (int i = 0; i < 8; ++i) {
        const int nt = i * 8 + wave;
        const int nn = nt * 16 + lq;
        if (nn < 1000) {
            #pragma unroll
            for (int r = 0; r < 4; ++r) {
                int p = p0 + quad * 4 + r;
                if (p < 1000)
                    out[((size_t)b * 1000 + p) * 1000 + nn] = ev[i][r] * inv[r];
            }
        }
    }
}

// ---------------------------------------------------------------------------
extern "C" void kernel_launch(void* const* d_in, const int* in_sizes, int n_in,
                              void* d_out, int out_size, void* d_ws, size_t ws_size,
                              hipStream_t stream)
{
    const float* eln   = (const float*)d_in[0];
    const float* attr  = (const float*)d_in[1];
    const float* nodes = (const float*)d_in[2];
    const float* mask  = (const float*)d_in[3];
    const float* Wq_s  = (const float*)d_in[4];
    const float* Wk_s  = (const float*)d_in[5];
    const float* Wv_s  = (const float*)d_in[6];
    const float* Wq_t  = (const float*)d_in[7];
    const float* Wk_t  = (const float*)d_in[8];
    const float* Wv_t  = (const float*)d_in[9];
    const float* Wc_s  = (const float*)d_in[10];
    const float* bc_s  = (const float*)d_in[11];
    const float* Wc_t  = (const float*)d_in[12];
    const float* bc_t  = (const float*)d_in[13];
    const float* Wg    = (const float*)d_in[14];
    const float* bg    = (const float*)d_in[15];
    float* out = (float*)d_out;

    char* w = (char*)d_ws;
    const size_t KB_SZ = (size_t)64 * 1000 * 16 * 2;   // 2,048,000 B
    const size_t VT_SZ = (size_t)64 * 16 * 1024 * 2;   // 2,097,152 B
    const size_t H_SZ  = (size_t)8000 * 128 * 2;       // 2,048,000 B
    const size_t IN_SZ = (size_t)8000 * 160 * 2;       // 2,560,000 B
    const size_t EM_SZ = (size_t)8000 * 1000 * 2;      // 16,000,000 B
    __bf16* kb_s  = (__bf16*)w;           w += KB_SZ;
    __bf16* kb_t  = (__bf16*)w;           w += KB_SZ;
    __bf16* qb_s  = (__bf16*)w;           w += KB_SZ;
    __bf16* qb_t  = (__bf16*)w;           w += KB_SZ;
    __bf16* vt_s  = (__bf16*)w;           w += VT_SZ;
    __bf16* vt_t  = (__bf16*)w;           w += VT_SZ;
    __bf16* att_s = (__bf16*)w;           w += H_SZ;
    __bf16* att_t = (__bf16*)w;           w += H_SZ;
    __bf16* gatedb = (__bf16*)w;          w += H_SZ;
    __bf16* nodesb = (__bf16*)w;          w += H_SZ;
    __bf16* inb    = (__bf16*)w;          w += IN_SZ;
    __bf16* emaskb = (__bf16*)w;          w += EM_SZ;
    __bf16* Wtb    = (__bf16*)w;          w += 320000;
    // total ~39.5 MB (< 41 MB proven)

    // zero V-transposed pads so tail B-frags are exact zeros
    hipMemsetAsync(vt_s, 0, 2 * VT_SZ, stream);

    prep_kernel<<<dim3(2874), 256, 0, stream>>>(
        mask, nodes, eln, attr, Wk_s, Wv_s, Wk_t, Wv_t, Wq_s, Wq_t, Wg,
        Wc_s, Wc_t, emaskb, nodesb, inb, Wtb);
    proj_mfma_kernel<<<dim3(125, 6), 256, 0, stream>>>(
        nodesb, inb, Wtb, kb_s, vt_s, kb_t, vt_t, qb_s, qb_t);
    attn_mfma_kernel<<<dim3(32, 2, 8), 256, 0, stream>>>(
        qb_s, qb_t, kb_s, kb_t, vt_s, vt_t, emaskb, att_s, att_t);
    combine_mfma_kernel<<<dim3(125, 8), 256, 0, stream>>>(
        att_s, att_t, inb, Wtb, bc_s, bc_t, bg, gatedb);
    pointer_softmax_kernel<<<dim3(63, 8), 512, 0, stream>>>(
        gatedb, nodesb, emaskb, out);
}

// Round 12
// 215.865 us; speedup vs baseline: 1.0351x; 1.0351x over previous
//
#include <hip/hip_runtime.h>
#include <math.h>

#define BB 8
#define PP 1000
#define NN 1000
#define EE 128
#define HH 8
#define DD 16

#define INV_SQRT_E 0.08838834764831845f   // 1/sqrt(128)
#define LOG2E      1.4426950408889634f
#define QSCALE     0.3606737602222409f     // (1/sqrt(16)) * log2(e), folded into Q at proj

typedef short short8_t __attribute__((ext_vector_type(8)));
typedef float f32x4    __attribute__((ext_vector_type(4)));
typedef float f32x16   __attribute__((ext_vector_type(16)));
typedef __bf16 bf16x4  __attribute__((ext_vector_type(4)));
typedef __bf16 bf16x8  __attribute__((ext_vector_type(8)));

__device__ __forceinline__ float sigmoid_fast(float x) {
    return 1.f / (1.f + __expf(-x));
}
__device__ __forceinline__ float tanh_fast(float x) {
    x = fminf(fmaxf(x, -15.f), 15.f);
    float e = __expf(2.f * x);
    return (e - 1.f) / (e + 1.f);
}

__device__ __forceinline__ f32x4 mfma16(short8_t a, short8_t b, f32x4 c) {
    return __builtin_amdgcn_mfma_f32_16x16x32_bf16(a, b, c, 0, 0, 0);
}
__device__ __forceinline__ f32x16 mfma32(short8_t a, short8_t b, f32x16 c) {
    return __builtin_amdgcn_mfma_f32_32x32x16_bf16(a, b, c, 0, 0, 0);
}

// sum across the 16 lanes of a DPP row (pure VALU butterfly)
__device__ __forceinline__ float sum16(float x) {
    int v;
    v = __builtin_amdgcn_update_dpp(0, __builtin_bit_cast(int, x), 0xB1, 0xF, 0xF, true);
    x += __builtin_bit_cast(float, v);
    v = __builtin_amdgcn_update_dpp(0, __builtin_bit_cast(int, x), 0x4E, 0xF, 0xF, true);
    x += __builtin_bit_cast(float, v);
    v = __builtin_amdgcn_update_dpp(0, __builtin_bit_cast(int, x), 0x141, 0xF, 0xF, true);
    x += __builtin_bit_cast(float, v);
    v = __builtin_amdgcn_update_dpp(0, __builtin_bit_cast(int, x), 0x140, 0xF, 0xF, true);
    x += __builtin_bit_cast(float, v);
    return x;
}

// ---------------------------------------------------------------------------
// K0: FUSED prep, fat grid-stride threads (16 floats each).
// Grid segments:
//  [0,1954)      emaskb = (bf16)(mask*log2e)  -- LOG2 DOMAIN  (8M elems)
//  [1954,2204)   nodesb = (bf16)nodes               (1.024M elems)
//  [2204,2829)   inb = concat(eln,attr,0) bf16      (8000x160)
//  [2829,2874)   Wtb = transposed bf16 weights      (9 x 5 k-tiles)
// Wtb offsets: 0:k_s 16384:v_s 32768:k_t 49152:v_t 65536:q_s 86016:q_t
//              106496:g 126976:c_s 143360:c_t
// ---------------------------------------------------------------------------
__global__ __launch_bounds__(256) void prep_kernel(
    const float* __restrict__ mask, const float* __restrict__ nodes,
    const float* __restrict__ eln,  const float* __restrict__ attr,
    const float* __restrict__ Wk_s, const float* __restrict__ Wv_s,
    const float* __restrict__ Wk_t, const float* __restrict__ Wv_t,
    const float* __restrict__ Wq_s, const float* __restrict__ Wq_t,
    const float* __restrict__ Wg,   const float* __restrict__ Wc_s,
    const float* __restrict__ Wc_t,
    __bf16* __restrict__ emaskb, __bf16* __restrict__ nodesb,
    __bf16* __restrict__ inb, __bf16* __restrict__ Wtb)
{
    const int bx = blockIdx.x;
    __shared__ float tile[32][129];
    if (bx < 1954) {
        int base = (bx * 256 + threadIdx.x) * 16;
        if (base < 8000000) {
            #pragma unroll
            for (int q = 0; q < 4; ++q) {
                float4 v = *(const float4*)&mask[base + q * 4];
                bf16x4 p = { (__bf16)(v.x * LOG2E), (__bf16)(v.y * LOG2E),
                             (__bf16)(v.z * LOG2E), (__bf16)(v.w * LOG2E) };
                *(bf16x4*)&emaskb[base + q * 4] = p;
            }
        }
    } else if (bx < 2204) {
        int base = ((bx - 1954) * 256 + threadIdx.x) * 16;   // 1,024,000 exact
        #pragma unroll
        for (int q = 0; q < 4; ++q) {
            float4 v = *(const float4*)&nodes[base + q * 4];
            bf16x4 p = { (__bf16)v.x, (__bf16)v.y, (__bf16)v.z, (__bf16)v.w };
            *(bf16x4*)&nodesb[base + q * 4] = p;
        }
    } else if (bx < 2829) {
        int t = (bx - 2204) * 256 + threadIdx.x;             // 160,000 exact
        int row = t / 20, seg = t - row * 20;
        bf16x8 o = {};
        if (seg < 16) {
            const float* p = &eln[(size_t)row * 128 + seg * 8];
            float4 a = *(const float4*)p, b = *(const float4*)(p + 4);
            o = bf16x8{ (__bf16)a.x, (__bf16)a.y, (__bf16)a.z, (__bf16)a.w,
                        (__bf16)b.x, (__bf16)b.y, (__bf16)b.z, (__bf16)b.w };
        } else if (seg == 16) {
            float4 a = *(const float4*)&attr[(size_t)row * 4];
            o = bf16x8{ (__bf16)a.x, (__bf16)a.y, (__bf16)a.z, (__bf16)a.w,
                        (__bf16)0.f, (__bf16)0.f, (__bf16)0.f, (__bf16)0.f };
        }
        *(bf16x8*)&inb[(size_t)row * 160 + seg * 8] = o;
    } else {
        int idx = bx - 2829;
        int m = idx / 5, kt = idx - m * 5;
        const float* srcs[9] = {Wk_s, Wv_s, Wk_t, Wv_t, Wq_s, Wq_t, Wg, Wc_s, Wc_t};
        const int   srcKs[9] = {128, 128, 128, 128, 132, 132, 132, 128, 128};
        const int   kpads[9] = {128, 128, 128, 128, 160, 160, 160, 128, 128};
        const size_t offs[9] = {0, 16384, 32768, 49152, 65536, 86016, 106496, 126976, 143360};
        const int kp = kpads[m];
        if (kt * 32 >= kp) return;
        const float* src = srcs[m];
        const int sK = srcKs[m];
        const size_t off = offs[m];
        const int tid = threadIdx.x;
        for (int j = tid; j < 32 * 128; j += 256) {
            int kk = j >> 7, n = j & 127;
            int k = kt * 32 + kk;
            tile[kk][n] = (k < sK) ? src[(size_t)k * 128 + n] : 0.f;
        }
        __syncthreads();
        for (int j = tid; j < 32 * 128; j += 256) {
            int n = j >> 5, kk = j & 31;
            Wtb[off + (size_t)n * kp + kt * 32 + kk] = (__bf16)tile[kk][n];
        }
    }
}

// ---------------------------------------------------------------------------
// K1: MFMA projections. Wave = 16 rows x 128 cols. blockIdx.y = wsel:
// 0..3 kv (A=nodesb,K=128), 4..5 q (A=inb,K=160, scaled by log2e/sqrt(D)).
// ---------------------------------------------------------------------------
template<int NC>
__device__ __forceinline__ void proj_body(
    const __bf16* __restrict__ A, const __bf16* __restrict__ W,
    f32x4 acc[8], int r0, int quad, int lq)
{
    const int K = NC * 32;
    short8_t aF[NC];
    #pragma unroll
    for (int c = 0; c < NC; ++c)
        aF[c] = *(const short8_t*)&A[(size_t)(r0 + lq) * K + c * 32 + quad * 8];
    #pragma unroll
    for (int nt = 0; nt < 8; ++nt) {
        acc[nt] = f32x4{0.f, 0.f, 0.f, 0.f};
        #pragma unroll
        for (int c = 0; c < NC; ++c) {
            short8_t bF = *(const short8_t*)&W[(size_t)(nt * 16 + lq) * K + c * 32 + quad * 8];
            acc[nt] = mfma16(aF[c], bF, acc[nt]);
        }
    }
}

__global__ __launch_bounds__(256) void proj_mfma_kernel(
    const __bf16* __restrict__ nodesb, const __bf16* __restrict__ inb,
    const __bf16* __restrict__ Wtb,
    __bf16* __restrict__ kb_s, __bf16* __restrict__ vt_s,
    __bf16* __restrict__ kb_t, __bf16* __restrict__ vt_t,
    __bf16* __restrict__ qb_s, __bf16* __restrict__ qb_t)
{
    const int wsel = blockIdx.y;
    const int wave = threadIdx.x >> 6, lane = threadIdx.x & 63;
    const int quad = lane >> 4, lq = lane & 15;
    const int r0 = blockIdx.x * 64 + wave * 16;

    f32x4 acc[8];
    if (wsel < 4) {
        proj_body<4>(nodesb, Wtb + (size_t)wsel * 16384, acc, r0, quad, lq);
    } else {
        proj_body<5>(inb, Wtb + 65536 + (size_t)(wsel - 4) * 20480, acc, r0, quad, lq);
    }

    if (wsel == 0 || wsel == 2) {
        __bf16* O = (wsel == 0) ? kb_s : kb_t;
        #pragma unroll
        for (int r = 0; r < 4; ++r) {
            int m = r0 + quad * 4 + r;
            int b = m / 1000, n = m - b * 1000;
            #pragma unroll
            for (int nt = 0; nt < 8; ++nt)
                O[(((size_t)(b * 8 + nt) * 1000 + n) << 4) + lq] = (__bf16)acc[nt][r];
        }
    } else if (wsel == 4 || wsel == 5) {
        __bf16* O = (wsel == 4) ? qb_s : qb_t;
        #pragma unroll
        for (int r = 0; r < 4; ++r) {
            int m = r0 + quad * 4 + r;
            int b = m / 1000, n = m - b * 1000;
            #pragma unroll
            for (int nt = 0; nt < 8; ++nt)
                O[(((size_t)(b * 8 + nt) * 1000 + n) << 4) + lq] =
                    (__bf16)(acc[nt][r] * QSCALE);
        }
    } else {
        __bf16* O = (wsel == 1) ? vt_s : vt_t;
        #pragma unroll
        for (int r = 0; r < 4; ++r) {
            int m = r0 + quad * 4 + r;
            int b = m / 1000, n = m - b * 1000;
            int rr = n & 31;
            int pos = (n & ~31) + ((rr < 16) ? (rr << 1) : (((rr - 16) << 1) | 1));
            #pragma unroll
            for (int nt = 0; nt < 8; ++nt)
                O[(((size_t)(b * 8 + nt) * 16 + lq) << 10) + pos] = (__bf16)acc[nt][r];
        }
    }
}

// ---------------------------------------------------------------------------
// K2: MFMA flash attention v14: R10 structure (branch-fused, mask prefetch,
// LDS block-XOR swizzle, explicit v_add mask) + T5 s_setprio(1) around the
// MFMA clusters. Waves in a block are barrier-free and phase-staggered, so
// priority lets the MFMA-entering wave win issue arbitration (m191: +4-7%).
// ---------------------------------------------------------------------------
__global__ __launch_bounds__(256) void attn_mfma_kernel(
    const __bf16* __restrict__ qb_s, const __bf16* __restrict__ qb_t,
    const __bf16* __restrict__ kb_s, const __bf16* __restrict__ kb_t,
    const __bf16* __restrict__ vt_s, const __bf16* __restrict__ vt_t,
    const __bf16* __restrict__ emaskb,
    __bf16* __restrict__ att_s, __bf16* __restrict__ att_t)
{
    const int b    = blockIdx.z;
    const int wave = threadIdx.x >> 6;
    const int h    = blockIdx.y * 4 + wave;
    const int lane = threadIdx.x & 63;
    const int quad = lane >> 4, lq = lane & 15;
    const int col  = lane & 31;         // 32x32 column (= p for scores)
    const int half = lane >> 5;         // 32x32 row-half
    const int bh = b * HH + h;
    const int p0 = blockIdx.x * 32;

    // S[wave][parity][branch][p][slot], slot-blocks XOR-swizzled by row
    __shared__ __align__(16) __bf16 S[4][2][2][32][40];

    // write-side swizzle for this lane's P row (row = col)
    const int cw = (col >> 3) & 3;
    // read-side swizzled byte offsets (row = t*16+lq, block = quad ^ cr_t)
    const int r0q = 8 * (quad ^ ((lq >> 3) & 1));        // t=0: cr = 0|1
    const int r1q = 8 * (quad ^ (2 | ((lq >> 3) & 1)));  // t=1: cr = 2|3

    int pq = p0 + col; if (pq > 999) pq = 999;
    short8_t qS = *(const short8_t*)&qb_s[(((size_t)bh * 1000 + pq) << 4) + half * 8];
    short8_t qT = *(const short8_t*)&qb_t[(((size_t)bh * 1000 + pq) << 4) + half * 8];
    const __bf16* mp = emaskb + ((size_t)b * 1000 + pq) * 1000 + 4 * half;

    short8_t onesB = { (short)0x3F80, (short)0x3F80, (short)0x3F80, (short)0x3F80,
                       (short)0x3F80, (short)0x3F80, (short)0x3F80, (short)0x3F80 };

    f32x4 oS[2] = { {0.f,0.f,0.f,0.f}, {0.f,0.f,0.f,0.f} };
    f32x4 lS[2] = { {0.f,0.f,0.f,0.f}, {0.f,0.f,0.f,0.f} };
    f32x4 oT[2] = { {0.f,0.f,0.f,0.f}, {0.f,0.f,0.f,0.f} };
    f32x4 lT[2] = { {0.f,0.f,0.f,0.f}, {0.f,0.f,0.f,0.f} };

    const size_t kqoff = (((size_t)bh * 1000) << 4) + half * 8;
    const size_t voff  = (((size_t)bh * 16 + lq) << 10) + quad * 8;

    short8_t kScur = *(const short8_t*)&kb_s[kqoff + ((size_t)col << 4)];
    short8_t kTcur = *(const short8_t*)&kb_t[kqoff + ((size_t)col << 4)];
    short8_t vScur = *(const short8_t*)&vt_s[voff];
    short8_t vTcur = *(const short8_t*)&vt_t[voff];
    bf16x4 mc[4];
    #pragma unroll
    for (int g = 0; g < 4; ++g) mc[g] = *(const bf16x4*)&mp[8 * g];

    #pragma unroll 2
    for (int n0 = 0; n0 < 992; n0 += 32) {
        const int par = (n0 >> 5) & 1;
        int nk = n0 + 32 + col; if (nk > 999) nk = 999;
        short8_t kSn = *(const short8_t*)&kb_s[kqoff + ((size_t)nk << 4)];
        short8_t kTn = *(const short8_t*)&kb_t[kqoff + ((size_t)nk << 4)];
        short8_t vSn = *(const short8_t*)&vt_s[voff + n0 + 32];
        short8_t vTn = *(const short8_t*)&vt_t[voff + n0 + 32];
        bf16x4 mn[4];
        #pragma unroll
        for (int g = 0; g < 4; ++g)
            mn[g] = *(const bf16x4*)&mp[n0 + 32 + 8 * g];

        // shared mask floats (current tile, prefetched last iteration)
        float mf[16];
        #pragma unroll
        for (int g = 0; g < 4; ++g)
            #pragma unroll
            for (int j = 0; j < 4; ++j)
                mf[4 * g + j] = (float)mc[g][j];

        // branch S scores
        __builtin_amdgcn_s_setprio(1);
        f32x16 sS = mfma32(kScur, qS, f32x16{});
        __builtin_amdgcn_s_setprio(0);
        #pragma unroll
        for (int g = 0; g < 4; ++g) {
            bf16x4 pk;
            #pragma unroll
            for (int j = 0; j < 4; ++j)
                pk[j] = (__bf16)__builtin_amdgcn_exp2f(sS[4 * g + j] + mf[4 * g + j]);
            *(bf16x4*)&S[wave][par][0][col][8 * (g ^ cw) + 4 * half] = pk;
        }

        // branch T scores (latency hidden by PV-S below)
        __builtin_amdgcn_s_setprio(1);
        f32x16 sT = mfma32(kTcur, qT, f32x16{});

        {
            short8_t aP0 = *(const short8_t*)&S[wave][par][0][lq][r0q];
            oS[0] = mfma16(aP0, vScur, oS[0]);
            lS[0] = mfma16(aP0, onesB, lS[0]);
            short8_t aP1 = *(const short8_t*)&S[wave][par][0][16 + lq][r1q];
            oS[1] = mfma16(aP1, vScur, oS[1]);
            lS[1] = mfma16(aP1, onesB, lS[1]);
        }
        __builtin_amdgcn_s_setprio(0);

        #pragma unroll
        for (int g = 0; g < 4; ++g) {
            bf16x4 pk;
            #pragma unroll
            for (int j = 0; j < 4; ++j)
                pk[j] = (__bf16)__builtin_amdgcn_exp2f(sT[4 * g + j] + mf[4 * g + j]);
            *(bf16x4*)&S[wave][par][1][col][8 * (g ^ cw) + 4 * half] = pk;
        }

        __builtin_amdgcn_s_setprio(1);
        {
            short8_t aP0 = *(const short8_t*)&S[wave][par][1][lq][r0q];
            oT[0] = mfma16(aP0, vTcur, oT[0]);
            lT[0] = mfma16(aP0, onesB, lT[0]);
            short8_t aP1 = *(const short8_t*)&S[wave][par][1][16 + lq][r1q];
            oT[1] = mfma16(aP1, vTcur, oT[1]);
            lT[1] = mfma16(aP1, onesB, lT[1]);
        }
        __builtin_amdgcn_s_setprio(0);

        kScur = kSn; kTcur = kTn; vScur = vSn; vTcur = vTn;
        #pragma unroll
        for (int g = 0; g < 4; ++g) mc[g] = mn[g];
    }

    // tail: keys 992..999 == group g=0 of both halves; groups 1..3 zeroed
    // (XOR is a bijection on blocks 0..3, so writing all 4 g-blocks covers all)
    {
        float mft[4];
        #pragma unroll
        for (int j = 0; j < 4; ++j) mft[j] = (float)mc[0][j];
        bf16x4 z = {};

        f32x16 sS = mfma32(kScur, qS, f32x16{});
        bf16x4 pkS;
        #pragma unroll
        for (int j = 0; j < 4; ++j)
            pkS[j] = (__bf16)__builtin_amdgcn_exp2f(sS[j] + mft[j]);
        *(bf16x4*)&S[wave][1][0][col][8 * (0 ^ cw) + 4 * half] = pkS;
        #pragma unroll
        for (int g = 1; g < 4; ++g)
            *(bf16x4*)&S[wave][1][0][col][8 * (g ^ cw) + 4 * half] = z;

        f32x16 sT = mfma32(kTcur, qT, f32x16{});

        {
            short8_t aP0 = *(const short8_t*)&S[wave][1][0][lq][r0q];
            oS[0] = mfma16(aP0, vScur, oS[0]);
            lS[0] = mfma16(aP0, onesB, lS[0]);
            short8_t aP1 = *(const short8_t*)&S[wave][1][0][16 + lq][r1q];
            oS[1] = mfma16(aP1, vScur, oS[1]);
            lS[1] = mfma16(aP1, onesB, lS[1]);
        }

        bf16x4 pkT;
        #pragma unroll
        for (int j = 0; j < 4; ++j)
            pkT[j] = (__bf16)__builtin_amdgcn_exp2f(sT[j] + mft[j]);
        *(bf16x4*)&S[wave][1][1][col][8 * (0 ^ cw) + 4 * half] = pkT;
        #pragma unroll
        for (int g = 1; g < 4; ++g)
            *(bf16x4*)&S[wave][1][1][col][8 * (g ^ cw) + 4 * half] = z;

        {
            short8_t aP0 = *(const short8_t*)&S[wave][1][1][lq][r0q];
            oT[0] = mfma16(aP0, vTcur, oT[0]);
            lT[0] = mfma16(aP0, onesB, lT[0]);
            short8_t aP1 = *(const short8_t*)&S[wave][1][1][16 + lq][r1q];
            oT[1] = mfma16(aP1, vTcur, oT[1]);
            lT[1] = mfma16(aP1, onesB, lT[1]);
        }
    }

    #pragma unroll
    for (int t = 0; t < 2; ++t)
        #pragma unroll
        for (int r = 0; r < 4; ++r) {
            int p = p0 + t * 16 + quad * 4 + r;
            if (p < 1000) {
                size_t oidx = ((size_t)b * 1000 + p) * 128 + h * 16 + lq;
                att_s[oidx] = (__bf16)(oS[t][r] / lS[t][r]);
                att_t[oidx] = (__bf16)(oT[t][r] / lT[t][r]);
            }
        }
}

// ---------------------------------------------------------------------------
// K3: MFMA combine WITH INLINE GATE, nt-PARALLEL: grid (125, 8) x 256.
// ---------------------------------------------------------------------------
__global__ __launch_bounds__(256) void combine_mfma_kernel(
    const __bf16* __restrict__ att_s, const __bf16* __restrict__ att_t,
    const __bf16* __restrict__ inb, const __bf16* __restrict__ Wtb,
    const float* __restrict__ bc_s, const float* __restrict__ bc_t,
    const float* __restrict__ bg, __bf16* __restrict__ gatedb)
{
    const int wave = threadIdx.x >> 6, lane = threadIdx.x & 63;
    const int quad = lane >> 4, lq = lane & 15;
    const int r0 = blockIdx.x * 64 + wave * 16;
    const int nt = blockIdx.y;                 // 0..7
    const __bf16* Wgp = Wtb + 106496;
    const __bf16* Ws  = Wtb + 126976;
    const __bf16* Wt  = Wtb + 143360;

    short8_t aS[4], aT[4], aG[5];
    #pragma unroll
    for (int c = 0; c < 4; ++c) {
        aS[c] = *(const short8_t*)&att_s[(size_t)(r0 + lq) * 128 + c * 32 + quad * 8];
        aT[c] = *(const short8_t*)&att_t[(size_t)(r0 + lq) * 128 + c * 32 + quad * 8];
    }
    #pragma unroll
    for (int c = 0; c < 5; ++c)
        aG[c] = *(const short8_t*)&inb[(size_t)(r0 + lq) * 160 + c * 32 + quad * 8];

    f32x4 accS = {0.f,0.f,0.f,0.f}, accT = accS, accG = accS;
    #pragma unroll
    for (int c = 0; c < 4; ++c) {
        short8_t bS = *(const short8_t*)&Ws[(size_t)(nt * 16 + lq) * 128 + c * 32 + quad * 8];
        short8_t bT = *(const short8_t*)&Wt[(size_t)(nt * 16 + lq) * 128 + c * 32 + quad * 8];
        accS = mfma16(aS[c], bS, accS);
        accT = mfma16(aT[c], bT, accT);
    }
    #pragma unroll
    for (int c = 0; c < 5; ++c) {
        short8_t bG = *(const short8_t*)&Wgp[(size_t)(nt * 16 + lq) * 160 + c * 32 + quad * 8];
        accG = mfma16(aG[c], bG, accG);
    }
    int f = nt * 16 + lq;
    float b1 = bc_s[f], b2 = bc_t[f], b3 = bg[f];
    #pragma unroll
    for (int r = 0; r < 4; ++r) {
        int m = r0 + quad * 4 + r;
        float g = sigmoid_fast(accG[r] + b3);
        float val = g * (accS[r] + b1) + (1.f - g) * (accT[r] + b2);
        gatedb[(size_t)m * 128 + f] = (__bf16)val;
    }
}

// ---------------------------------------------------------------------------
// K4: FUSED pointer scores + clip + log2-mask + row softmax -> probs in d_out.
// 8 waves (512 threads).
// ---------------------------------------------------------------------------
__global__ __launch_bounds__(512) void pointer_softmax_kernel(
    const __bf16* __restrict__ gb, const __bf16* __restrict__ nb,
    const __bf16* __restrict__ emaskb, float* __restrict__ out)
{
    const int b    = blockIdx.y;
    const int p0   = blockIdx.x * 16;
    const int wave = threadIdx.x >> 6;          // 0..7
    const int lane = threadIdx.x & 63;
    const int quad = lane >> 4, lq = lane & 15;

    __shared__ float Spart[8][16];

    short8_t aF[4];
    {
        int pp = p0 + lq; if (pp > 999) pp = 999;
        const __bf16* arow = gb + (((size_t)b * 1000 + pp) << 7) + quad * 8;
        #pragma unroll
        for (int kc = 0; kc < 4; ++kc) aF[kc] = *(const short8_t*)&arow[kc * 32];
    }

    float ev[8][4];
    float psum[4] = {0.f, 0.f, 0.f, 0.f};

    #pragma unroll
    for (int i = 0; i < 8; ++i) {
        const int nt = i * 8 + wave;          // 0..63
        const int nn = nt * 16 + lq;
        const bool nv = nn < 1000;
        int nc = nv ? nn : 999;
        const __bf16* brow = nb + (((size_t)b * 1000 + nc) << 7) + quad * 8;
        f32x4 acc = {0.f, 0.f, 0.f, 0.f};
        #pragma unroll
        for (int kc = 0; kc < 4; ++kc) {
            short8_t bF = *(const short8_t*)&brow[kc * 32];
            acc = mfma16(aF[kc], bF, acc);
        }
        #pragma unroll
        for (int r = 0; r < 4; ++r) {
            int p = p0 + quad * 4 + r;
            bool v = nv && (p < 1000);
            size_t midx = v ? ((size_t)b * 1000 + p) * 1000 + nn : 0;
            float m2 = (float)emaskb[midx];
            float sc = 10.f * tanh_fast(acc[r] * INV_SQRT_E);
            float ee = v ? __builtin_amdgcn_exp2f(sc * LOG2E + m2) : 0.f;
            ev[i][r] = ee;
            psum[r] += ee;
        }
    }

    #pragma unroll
    for (int r = 0; r < 4; ++r) psum[r] = sum16(psum[r]);
    if (lq == 0) {
        #pragma unroll
        for (int r = 0; r < 4; ++r) Spart[wave][quad * 4 + r] = psum[r];
    }
    __syncthreads();
    float inv[4];
    #pragma unroll
    for (int r = 0; r < 4; ++r) {
        int row = quad * 4 + r;
        float s = 0.f;
        #pragma unroll
        for (int wv = 0; wv < 8; ++wv) s += Spart[wv][row];
        inv[r] = 1.f / s;
    }

    #pragma unroll
    for (int i = 0; i < 8; ++i) {
        const int nt = i * 8 + wave;
        const int nn = nt * 16 + lq;
        if (nn < 1000) {
            #pragma unroll
            for (int r = 0; r < 4; ++r) {
                int p = p0 + quad * 4 + r;
                if (p < 1000)
                    out[((size_t)b * 1000 + p) * 1000 + nn] = ev[i][r] * inv[r];
            }
        }
    }
}

// ---------------------------------------------------------------------------
extern "C" void kernel_launch(void* const* d_in, const int* in_sizes, int n_in,
                              void* d_out, int out_size, void* d_ws, size_t ws_size,
                              hipStream_t stream)
{
    const float* eln   = (const float*)d_in[0];
    const float* attr  = (const float*)d_in[1];
    const float* nodes = (const float*)d_in[2];
    const float* mask  = (const float*)d_in[3];
    const float* Wq_s  = (const float*)d_in[4];
    const float* Wk_s  = (const float*)d_in[5];
    const float* Wv_s  = (const float*)d_in[6];
    const float* Wq_t  = (const float*)d_in[7];
    const float* Wk_t  = (const float*)d_in[8];
    const float* Wv_t  = (const float*)d_in[9];
    const float* Wc_s  = (const float*)d_in[10];
    const float* bc_s  = (const float*)d_in[11];
    const float* Wc_t  = (const float*)d_in[12];
    const float* bc_t  = (const float*)d_in[13];
    const float* Wg    = (const float*)d_in[14];
    const float* bg    = (const float*)d_in[15];
    float* out = (float*)d_out;

    char* w = (char*)d_ws;
    const size_t KB_SZ = (size_t)64 * 1000 * 16 * 2;   // 2,048,000 B
    const size_t VT_SZ = (size_t)64 * 16 * 1024 * 2;   // 2,097,152 B
    const size_t H_SZ  = (size_t)8000 * 128 * 2;       // 2,048,000 B
    const size_t IN_SZ = (size_t)8000 * 160 * 2;       // 2,560,000 B
    const size_t EM_SZ = (size_t)8000 * 1000 * 2;      // 16,000,000 B
    __bf16* kb_s  = (__bf16*)w;           w += KB_SZ;
    __bf16* kb_t  = (__bf16*)w;           w += KB_SZ;
    __bf16* qb_s  = (__bf16*)w;           w += KB_SZ;
    __bf16* qb_t  = (__bf16*)w;           w += KB_SZ;
    __bf16* vt_s  = (__bf16*)w;           w += VT_SZ;
    __bf16* vt_t  = (__bf16*)w;           w += VT_SZ;
    __bf16* att_s = (__bf16*)w;           w += H_SZ;
    __bf16* att_t = (__bf16*)w;           w += H_SZ;
    __bf16* gatedb = (__bf16*)w;          w += H_SZ;
    __bf16* nodesb = (__bf16*)w;          w += H_SZ;
    __bf16* inb    = (__bf16*)w;          w += IN_SZ;
    __bf16* emaskb = (__bf16*)w;          w += EM_SZ;
    __bf16* Wtb    = (__bf16*)w;          w += 320000;
    // total ~39.5 MB (< 41 MB proven)

    // zero V-transposed pads so tail B-frags are exact zeros
    hipMemsetAsync(vt_s, 0, 2 * VT_SZ, stream);

    prep_kernel<<<dim3(2874), 256, 0, stream>>>(
        mask, nodes, eln, attr, Wk_s, Wv_s, Wk_t, Wv_t, Wq_s, Wq_t, Wg,
        Wc_s, Wc_t, emaskb, nodesb, inb, Wtb);
    proj_mfma_kernel<<<dim3(125, 6), 256, 0, stream>>>(
        nodesb, inb, Wtb, kb_s, vt_s, kb_t, vt_t, qb_s, qb_t);
    attn_mfma_kernel<<<dim3(32, 2, 8), 256, 0, stream>>>(
        qb_s, qb_t, kb_s, kb_t, vt_s, vt_t, emaskb, att_s, att_t);
    combine_mfma_kernel<<<dim3(125, 8), 256, 0, stream>>>(
        att_s, att_t, inb, Wtb, bc_s, bc_t, bg, gatedb);
    pointer_softmax_kernel<<<dim3(63, 8), 512, 0, stream>>>(
        gatedb, nodesb, emaskb, out);
}